// Round 7
// baseline (70773.993 us; speedup 1.0000x reference)
//
#include <hip/hip_runtime.h>

#define T_LEN 8192
#define HH 128
#define G4 512
#define E_DIM 50
#define KT 23
#define START_T 21
#define STOP_T 22
#define NEGV -10000.0f

__device__ __forceinline__ float rl(float v, int lane) {
  return __int_as_float(__builtin_amdgcn_readlane(__float_as_int(v), lane));
}

template <int CTRL>
__device__ __forceinline__ float dppmov(float x) {
  return __int_as_float(
      __builtin_amdgcn_mov_dpp(__float_as_int(x), CTRL, 0xF, 0xF, true));
}

// lane-xor exchanges, all VALU (DPP), octet-safe:
__device__ __forceinline__ float xlane1(float x) { return dppmov<0xB1>(x); }  // quad_perm [1,0,3,2]
__device__ __forceinline__ float xlane2(float x) { return dppmov<0x4E>(x); }  // quad_perm [2,3,0,1]
// xor4 within octet = xor3 (quad_perm [3,2,1,0]) then xor7 (row_half_mirror)
__device__ __forceinline__ float xlane4(float x) { return dppmov<0x141>(dppmov<0x1B>(x)); }

// Packed fp32 FMA (VOP3P, arch-VGPR forced).
__device__ __forceinline__ void pkfma(float2& acc, const float2 w, const float2 h) {
  asm volatile("v_pk_fma_f32 %0, %1, %2, %0" : "+v"(acc) : "v"(w), "v"(h));
}

// LIGHT ballast: ONE dependent-chain FMA wave per CU (~1.6% VALU duty).
template <int BURST>
__device__ __forceinline__ void ballast_spin(const int* flag, int target, float seed,
                                             float* sink) {
  float x = seed;
  const float aa = 1.0000001f, bb = 1e-7f;
  while (__hip_atomic_load(flag, __ATOMIC_RELAXED, __HIP_MEMORY_SCOPE_AGENT) < target) {
#pragma unroll
    for (int q = 0; q < BURST; ++q) x = fmaf(x, aa, bb);
  }
  if (x == 12345.678f) *sink = x;   // unprovable -> loop not removable
}

// ---------------------------------------------------------------------------
// K1: pre[t][j] = Wih[row(j)] . x_t + bih + bhh
// Row permutation matches k_lstm lane j's owned row (R3-R5 proven):
//   r(j) = (g<<7) | dim,  g=(j>>1)&3, dim=((j>>3)<<1)|(j&1)   (bijective)
// ---------------------------------------------------------------------------
__global__ __launch_bounds__(512) void k_pre(
    const int* __restrict__ sentence, const float* __restrict__ embed,
    const float* __restrict__ Wih_f, const float* __restrict__ bih_f, const float* __restrict__ bhh_f,
    const float* __restrict__ Wih_b, const float* __restrict__ bih_b, const float* __restrict__ bhh_b,
    float* __restrict__ pre_f, float* __restrict__ pre_b)
{
  const int dir = blockIdx.x >> 8;
  const int t0 = (blockIdx.x & 255) * 32;
  const float* __restrict__ Wih = dir ? Wih_b : Wih_f;
  const float* __restrict__ bi  = dir ? bih_b : bih_f;
  const float* __restrict__ bh  = dir ? bhh_b : bhh_f;
  float* __restrict__ pre = dir ? pre_b : pre_f;
  const int j = threadIdx.x;
  const int r = (((j >> 1) & 3) << 7) | ((j >> 3) << 1) | (j & 1);
  float w[E_DIM];
  {
    const float2* w2 = (const float2*)(Wih + r * E_DIM);
#pragma unroll
    for (int q = 0; q < 25; ++q) { float2 v = w2[q]; w[2*q] = v.x; w[2*q+1] = v.y; }
  }
  const float bias = bi[r] + bh[r];
  __shared__ float xs[32][E_DIM];
  __shared__ int sidx[32];
  if (j < 32) sidx[j] = sentence[t0 + j];
  __syncthreads();
  for (int i = j; i < 32 * E_DIM; i += 512) {
    int tl = i / E_DIM;
    int e = i - tl * E_DIM;
    xs[tl][e] = embed[sidx[tl] * E_DIM + e];
  }
  __syncthreads();
  for (int tl = 0; tl < 32; ++tl) {
    float a0 = bias, a1 = 0.f;
#pragma unroll
    for (int e = 0; e < E_DIM; e += 2) {
      a0 += w[e]     * xs[tl][e];
      a1 += w[e + 1] * xs[tl][e + 1];
    }
    pre[(t0 + tl) * G4 + j] = a0 + a1;
  }
}

// ---------------------------------------------------------------------------
// K2: serial LSTM — R7: BOTH DIRS FUSED ON ONE CU (1024 threads, block 0).
//
// R6 falsified the "pressure-triggered parking" model (demand 110 < cap 128
// and the allocator STILL kept arch=52); combined with R3-R5 nulls the
// copy-tax model itself is doubtful (gfx90a+ VALU can source AGPRs in most
// encodings -> parking may be tax-free). The robust datum: step time ~1880cy
// across THREE different layouts (and R0's 4x LDS traffic cost only +20%)
// -> dominated by per-step FIXED costs (8-wave lockstep barrier + LDS
// turnaround + serial chain) at 2 waves/SIMD where nothing hides anything.
//
// R7: threads 0-511 = dir0, 512-1023 = dir1, identical R5 octet math per
// dir, ONE shared barrier per step, hbuf[dir][buf]. Wave->SIMD round-robin
// gives each SIMD 2 fwd + 2 bwd waves: one dir's chain stalls are filled by
// the other dir's MAC issue, and the per-step fixed costs are amortized
// over both directions. Win predicted under every live hypothesis.
// ---------------------------------------------------------------------------
__global__ __attribute__((amdgpu_flat_work_group_size(1024, 1024)))
void k_lstm(
    const float* __restrict__ Whh_f, const float* __restrict__ Whh_b,
    const float* __restrict__ h0, const float* __restrict__ c0,
    const float* __restrict__ pre_f, const float* __restrict__ pre_b,
    float* __restrict__ hcat, int* __restrict__ flag, float* __restrict__ sink)
{
  __shared__ float hbuf[2][2][HH];           // [dir][buf][dim]
  if (blockIdx.x >= 1) {
    if (threadIdx.x < 64)
      ballast_spin<512>(flag, 1, (float)(blockIdx.x * 64 + threadIdx.x), sink);
    return;
  }
  const int tid = threadIdx.x;
  const int dir = tid >> 9;                  // waves 0-7 dir0, 8-15 dir1
  const int j = tid & 511;
  const float* __restrict__ Whh = dir ? Whh_b : Whh_f;
  const float* __restrict__ pre = dir ? pre_b : pre_f;
  const int l = j & 7;               // lane-in-octet
  const int O = j >> 3;              // octet id (64) -> dims 2O, 2O+1
  const bool b0 = l & 1;             // item bit0 (dim parity ds)
  const bool b1 = (l >> 1) & 1;      // item bit1 (gate low bit)
  const bool b2 = (l >> 2) & 1;      // item bit2 (gate high bit)
  const int g = (l >> 1) & 3;        // this lane's final gate
  const int dim = (O << 1) | (l & 1);

  // wv[i*8 + 2k(+1)]: float2 halves of Whh[row(i)][chunk l+8k], row(i) =
  // ((i>>1)<<7) | (O<<1) | (i&1).  128 floats/thread.
  float2 wv[64];
#pragma unroll
  for (int i = 0; i < 8; ++i) {
    const int row = (((i >> 1) & 3) << 7) | (O << 1) | (i & 1);
    const float4* src = (const float4*)(Whh + row * HH);
#pragma unroll
    for (int k = 0; k < 4; ++k) {
      float4 v = src[l + 8 * k];
      wv[i * 8 + 2 * k]     = make_float2(v.x, v.y);
      wv[i * 8 + 2 * k + 1] = make_float2(v.z, v.w);
    }
  }
  // One-time pins (proven neutral; keeps loads hoisted out of the loop).
#define PIN8(B) asm volatile("" : "+v"(wv[B]), "+v"(wv[B+1]), "+v"(wv[B+2]), \
    "+v"(wv[B+3]), "+v"(wv[B+4]), "+v"(wv[B+5]), "+v"(wv[B+6]), "+v"(wv[B+7]))
  PIN8(0); PIN8(8); PIN8(16); PIN8(24); PIN8(32); PIN8(40); PIN8(48); PIN8(56);
#undef PIN8

  float c = c0[dir * HH + dim];
  if (g == 0) hbuf[dir][0][dim] = h0[dir * HH + dim];
  __syncthreads();
  float pcur = pre[(dir ? (T_LEN - 1) : 0) * G4 + j];
  float pn1  = pre[(dir ? (T_LEN - 2) : 1) * G4 + j];

  for (int s = 0; s < T_LEN; ++s) {
    const int t  = dir ? (T_LEN - 1 - s) : s;
    const int s2i = (s + 2 < T_LEN) ? (s + 2) : (T_LEN - 1);
    const int t2 = dir ? (T_LEN - 1 - s2i) : s2i;
    const float pn2 = pre[t2 * G4 + j];      // depth-2 prefetch

    const float4* h4 = (const float4*)hbuf[dir][s & 1];
    const float4 hc0 = h4[l];
    const float4 hc1 = h4[l + 8];
    const float4 hc2 = h4[l + 16];
    const float4 hc3 = h4[l + 24];
    const float2 h0a = make_float2(hc0.x, hc0.y), h0b = make_float2(hc0.z, hc0.w);
    const float2 h1a = make_float2(hc1.x, hc1.y), h1b = make_float2(hc1.z, hc1.w);
    const float2 h2a = make_float2(hc2.x, hc2.y), h2b = make_float2(hc2.z, hc2.w);
    const float2 h3a = make_float2(hc3.x, hc3.y), h3b = make_float2(hc3.z, hc3.w);

    float2 acc[8];
#pragma unroll
    for (int i = 0; i < 8; ++i) {
      acc[i] = make_float2(0.f, 0.f);
      pkfma(acc[i], wv[i * 8 + 0], h0a);
      pkfma(acc[i], wv[i * 8 + 1], h0b);
      pkfma(acc[i], wv[i * 8 + 2], h1a);
      pkfma(acc[i], wv[i * 8 + 3], h1b);
      pkfma(acc[i], wv[i * 8 + 4], h2a);
      pkfma(acc[i], wv[i * 8 + 5], h2b);
      pkfma(acc[i], wv[i * 8 + 6], h3a);
      pkfma(acc[i], wv[i * 8 + 7], h3b);
    }
    const float p0 = acc[0].x + acc[0].y;
    const float p1 = acc[1].x + acc[1].y;
    const float p2 = acc[2].x + acc[2].y;
    const float p3 = acc[3].x + acc[3].y;
    const float p4 = acc[4].x + acc[4].y;
    const float p5 = acc[5].x + acc[5].y;
    const float p6 = acc[6].x + acc[6].y;
    const float p7 = acc[7].x + acc[7].y;

    // reduce-scatter over octet: step1 xor4 (keep items with bit2==b2)
    const float u10 = b2 ? p4 : p0, v10 = b2 ? p0 : p4;
    const float u11 = b2 ? p5 : p1, v11 = b2 ? p1 : p5;
    const float u12 = b2 ? p6 : p2, v12 = b2 ? p2 : p6;
    const float u13 = b2 ? p7 : p3, v13 = b2 ? p3 : p7;
    const float q0 = u10 + xlane4(v10);
    const float q1 = u11 + xlane4(v11);
    const float q2 = u12 + xlane4(v12);
    const float q3 = u13 + xlane4(v13);
    // step2 xor2 (keep bit1==b1)
    const float u20 = b1 ? q2 : q0, v20 = b1 ? q0 : q2;
    const float u21 = b1 ? q3 : q1, v21 = b1 ? q1 : q3;
    const float r0 = u20 + xlane2(v20);
    const float r1 = u21 + xlane2(v21);
    // step3 xor1 (keep bit0==b0) -> full dot for row l
    const float u30 = b0 ? r1 : r0, v30 = b0 ? r0 : r1;
    const float dot = u30 + xlane1(v30);

    const float accv = dot + pcur;
    pcur = pn1; pn1 = pn2;

    const float sc = (g == 2) ? 2.0f : 1.0f;
    const float ev = __expf(-sc * accv);
    const float sg = 1.0f / (1.0f + ev);
    const float a  = (g == 2) ? (2.0f * sg - 1.0f) : sg;   // act of MY gate
    // gather the other 3 gates of my dim (lanes l^2, l^4, l^6)
    const float s2v = xlane2(a);   // gate g^1
    const float s4v = xlane4(a);   // gate g^2
    const float s6v = xlane2(s4v); // gate g^3
    // value of gate G sits at xor-distance (g^G)<<1: select by g
    const float iv  = b2 ? (b1 ? s6v : s4v) : (b1 ? s2v : a);
    const float fv  = b2 ? (b1 ? s4v : s6v) : (b1 ? a   : s2v);
    const float gv  = b2 ? (b1 ? s2v : a  ) : (b1 ? s6v : s4v);
    const float ovv = b2 ? (b1 ? a   : s2v) : (b1 ? s4v : s6v);
    c = fv * c + iv * gv;
    const float e2 = __expf(-2.0f * c);
    const float th = 2.0f / (1.0f + e2) - 1.0f;
    const float h = ovv * th;
    if (g == 0) {
      hbuf[dir][(s + 1) & 1][dim] = h;         // double-buffer: 1 barrier/step
      hcat[t * (2 * HH) + dir * HH + dim] = h; // fire-and-forget
    }
    __syncthreads();
  }
  if (tid == 0) atomicAdd(flag, 1);            // release ballast
}

// ---------------------------------------------------------------------------
// K3: feats32[t][k] = W_out[k] . hcat[t] + b_out[k]   (stride-32 layout)
// ---------------------------------------------------------------------------
__global__ __launch_bounds__(256) void k_feats(
    const float* __restrict__ hcat, const float* __restrict__ Wout,
    const float* __restrict__ bout, float* __restrict__ feats32)
{
  const int t0 = blockIdx.x * 32;
  __shared__ float hsh[32 * 257];
  __shared__ float wsh[KT * 256];
  __shared__ float bsh[KT];
  const int tid = threadIdx.x;
  for (int i = tid; i < 32 * 256; i += 256) {
    int tl = i >> 8, dd = i & 255;
    hsh[tl * 257 + dd] = hcat[(t0 + tl) * 256 + dd];
  }
  for (int i = tid; i < KT * 256; i += 256) wsh[i] = Wout[i];
  if (tid < KT) bsh[tid] = bout[tid];
  __syncthreads();
  for (int idx = tid; idx < 32 * KT; idx += 256) {
    int tl = idx & 31, k = idx >> 5;
    float a0 = bsh[k], a1 = 0.f, a2 = 0.f, a3 = 0.f;
#pragma unroll 8
    for (int dd = 0; dd < 256; dd += 4) {
      a0 += hsh[tl * 257 + dd + 0] * wsh[k * 256 + dd + 0];
      a1 += hsh[tl * 257 + dd + 1] * wsh[k * 256 + dd + 1];
      a2 += hsh[tl * 257 + dd + 2] * wsh[k * 256 + dd + 2];
      a3 += hsh[tl * 257 + dd + 3] * wsh[k * 256 + dd + 3];
    }
    feats32[(t0 + tl) * 32 + k] = ((a0 + a1) + (a2 + a3));
  }
}

// ---------------------------------------------------------------------------
// K4: sequential Viterbi forward (hit chain bound w/ ballast).
// ---------------------------------------------------------------------------
__global__ __launch_bounds__(64) void k_vit_fwd(
    const float* __restrict__ feats32, const float* __restrict__ trans,
    float* __restrict__ fvstore, float* __restrict__ out, int* __restrict__ misc,
    int* __restrict__ flag, float* __restrict__ sink)
{
  if (blockIdx.x >= 1) {
    ballast_spin<256>(flag, 1, (float)(blockIdx.x * 64 + threadIdx.x), sink);
    return;
  }
  const int j = threadIdx.x;
  const int j32 = j & 31;
  float trow[KT];
#pragma unroll
  for (int i = 0; i < KT; ++i)
    trow[i] = (j < KT) ? ((j == START_T || i == STOP_T) ? NEGV : trans[j * KT + i]) : NEGV;
  float fvn = (j == START_T) ? 0.0f : NEGV;
  float pf[8];
#pragma unroll
  for (int q = 0; q < 8; ++q) pf[q] = feats32[q * 32 + j32];

#define MAX3(a,b,cc) fmaxf(fmaxf((a),(b)),(cc))
#define CAND(i) (rl(fvn, (i)) + trow[(i)])

  for (int tb = 0; tb < T_LEN; tb += 8) {
#pragma unroll
    for (int q = 0; q < 8; ++q) {
      const int t = tb + q;
      fvstore[t * 64 + j] = fvn;                  // off-chain, all lanes
      float m0 = MAX3(CAND(0),  CAND(1),  CAND(2));
      float m1 = MAX3(CAND(3),  CAND(4),  CAND(5));
      float m2 = MAX3(CAND(6),  CAND(7),  CAND(8));
      float m3 = MAX3(CAND(9),  CAND(10), CAND(11));
      float m4 = MAX3(CAND(12), CAND(13), CAND(14));
      float m5 = MAX3(CAND(15), CAND(16), CAND(17));
      float m6 = MAX3(CAND(18), CAND(19), CAND(20));
      float m7 = fmaxf(CAND(21), CAND(22));
      float n0 = MAX3(m0, m1, m2);
      float n1 = MAX3(m3, m4, m5);
      float n2 = fmaxf(m6, m7);
      const float best = MAX3(n0, n1, n2);        // exact max: order-free
      fvn = best + pf[q];
      const int tpf = t + 8;
      const int tc = (tpf < T_LEN) ? tpf : (T_LEN - 1);
      pf[q] = feats32[tc * 32 + j32];             // unconditional
    }
  }
  const float trS = (j < KT) ? ((j == STOP_T) ? NEGV : trans[STOP_T * KT + j]) : 0.0f;
  float term = (j < KT) ? (fvn + trS) : -3.0e38f;
  int idx = (j < KT) ? j : 63;
#pragma unroll
  for (int off = 16; off >= 1; off >>= 1) {
    float ovl = __shfl_xor(term, off);
    int oi = __shfl_xor(idx, off);
    if (ovl > term || (ovl == term && oi < idx)) { term = ovl; idx = oi; }
  }
  if (j == 0) { out[0] = term; misc[0] = idx; atomicAdd(flag, 1); }
}

// ---------------------------------------------------------------------------
// K4b: parallel backpointers from stored fv (bitwise-identical candidates,
// strict-> first-max == jnp.argmax).
// ---------------------------------------------------------------------------
__global__ __launch_bounds__(256) void k_bptr(
    const float* __restrict__ fvstore, const float* __restrict__ trans,
    unsigned char* __restrict__ bptr)
{
  const int t0 = blockIdx.x * 32;
  __shared__ float fv[32 * 24];
  __shared__ float trc[KT * KT];
  const int tid = threadIdx.x;
  for (int i = tid; i < 32 * 24; i += 256) {
    int tl = i / 24, e = i - tl * 24;
    fv[i] = fvstore[(t0 + tl) * 64 + e];
  }
  for (int i = tid; i < KT * KT; i += 256) {
    int jj = i / KT, ii = i - jj * KT;
    trc[i] = (jj == START_T || ii == STOP_T) ? NEGV : trans[i];
  }
  __syncthreads();
  for (int p = tid; p < 32 * KT; p += 256) {
    int tl = p / KT, jj = p - tl * KT;
    const float* fvr = fv + tl * 24;
    const float* tr = trc + jj * KT;
    float best = fvr[0] + tr[0]; int bi = 0;
#pragma unroll
    for (int i = 1; i < KT; ++i) {
      float v = fvr[i] + tr[i];
      if (v > best) { best = v; bi = i; }
    }
    bptr[(t0 + tl) * KT + jj] = (unsigned char)bi;
  }
}

// ---------------------------------------------------------------------------
// K5: compose 32-step backpointer maps per chunk (parallel).
// ---------------------------------------------------------------------------
__global__ __launch_bounds__(64) void k_compose(
    const unsigned char* __restrict__ bptr, unsigned char* __restrict__ maps)
{
  const int c = blockIdx.x;
  const int lo = c * 32;
  __shared__ unsigned char rows[32 * 24];
  const int tid = threadIdx.x;
  for (int i = tid; i < 32 * KT; i += 64) {
    int tl = i / KT, e = i - tl * KT;
    rows[tl * 24 + e] = bptr[(lo + tl) * KT + e];
  }
  __syncthreads();
  if (tid < KT) {
    int x = tid;
    for (int tl = 31; tl >= 0; --tl) x = rows[tl * 24 + x];
    maps[c * KT + tid] = (unsigned char)x;
  }
}

// K6: sequential scan over 256 chunk maps.
__global__ __launch_bounds__(64) void k_backscan(
    const unsigned char* __restrict__ maps, const int* __restrict__ misc,
    int* __restrict__ btags)
{
  __shared__ unsigned char msh[256 * KT];
  const int tid = threadIdx.x;
  for (int i = tid; i < 256 * KT; i += 64) msh[i] = maps[i];
  __syncthreads();
  if (tid == 0) {
    int e = misc[0];
    for (int c = 255; c >= 0; --c) { btags[c] = e; e = msh[c * KT + e]; }
  }
}

// K7: evaluate interior path per chunk (parallel), write tags as floats.
__global__ __launch_bounds__(64) void k_backeval(
    const unsigned char* __restrict__ bptr, const int* __restrict__ btags,
    float* __restrict__ out)
{
  const int c = blockIdx.x;
  const int lo = c * 32;
  __shared__ unsigned char rows[32 * 24];
  __shared__ int tags[32];
  const int tid = threadIdx.x;
  for (int i = tid; i < 32 * KT; i += 64) {
    int tl = i / KT, e = i - tl * KT;
    rows[tl * 24 + e] = bptr[(lo + tl) * KT + e];
  }
  __syncthreads();
  if (tid == 0) {
    int tg = btags[c];
    tags[31] = tg;
    for (int tl = 31; tl >= 1; --tl) { tg = rows[tl * 24 + tg]; tags[tl - 1] = tg; }
  }
  __syncthreads();
  if (tid < 32) out[1 + lo + tid] = (float)tags[tid];
}

// ---------------------------------------------------------------------------
extern "C" void kernel_launch(void* const* d_in, const int* in_sizes, int n_in,
                              void* d_out, int out_size, void* d_ws, size_t ws_size,
                              hipStream_t stream) {
  const int*   sentence = (const int*)d_in[0];
  const float* embed    = (const float*)d_in[1];
  const float* Wih_f    = (const float*)d_in[2];
  const float* Whh_f    = (const float*)d_in[3];
  const float* bih_f    = (const float*)d_in[4];
  const float* bhh_f    = (const float*)d_in[5];
  const float* Wih_b    = (const float*)d_in[6];
  const float* Whh_b    = (const float*)d_in[7];
  const float* bih_b    = (const float*)d_in[8];
  const float* bhh_b    = (const float*)d_in[9];
  const float* Wout     = (const float*)d_in[10];
  const float* bout     = (const float*)d_in[11];
  const float* trans    = (const float*)d_in[12];
  const float* h0       = (const float*)d_in[13];
  const float* c0       = (const float*)d_in[14];
  float* out = (float*)d_out;

  float* ws = (float*)d_ws;
  float* pre_f = ws;                               // [T][512]
  float* pre_b = pre_f + (size_t)T_LEN * G4;       // [T][512]
  float* hcat  = pre_b + (size_t)T_LEN * G4;       // [T][256]
  float* feats32 = hcat + (size_t)T_LEN * 2 * HH;  // [T][32]
  unsigned char* bptr = (unsigned char*)(feats32 + (size_t)T_LEN * 32);
  unsigned char* maps = bptr + (size_t)T_LEN * KT;
  int* btags = (int*)(maps + 256 * KT);
  int* misc  = btags + 256;
  int* flags = misc + 8;                           // [0]=lstm done, [1]=vit done
  float* sink = (float*)(flags + 8);
  float* fvstore = pre_f;                          // [T][64], pre dead after k_lstm

  hipMemsetAsync(flags, 0, 8 * sizeof(int), stream);
  k_pre<<<512, 512, 0, stream>>>(sentence, embed, Wih_f, bih_f, bhh_f,
                                 Wih_b, bih_b, bhh_b, pre_f, pre_b);
  k_lstm<<<256, 1024, 0, stream>>>(Whh_f, Whh_b, h0, c0, pre_f, pre_b, hcat,
                                   flags + 0, sink);
  k_feats<<<256, 256, 0, stream>>>(hcat, Wout, bout, feats32);
  k_vit_fwd<<<256, 64, 0, stream>>>(feats32, trans, fvstore, out, misc,
                                    flags + 1, sink);
  k_bptr<<<256, 256, 0, stream>>>(fvstore, trans, bptr);
  k_compose<<<256, 64, 0, stream>>>(bptr, maps);
  k_backscan<<<1, 64, 0, stream>>>(maps, misc, btags);
  k_backeval<<<256, 64, 0, stream>>>(bptr, btags, out);
}

// Round 8
// 6998.685 us; speedup vs baseline: 10.1125x; 10.1125x over previous
//
#include <hip/hip_runtime.h>

#define T_LEN 8192
#define HH 128
#define G4 512
#define E_DIM 50
#define KT 23
#define START_T 21
#define STOP_T 22
#define NEGV -10000.0f

__device__ __forceinline__ float rl(float v, int lane) {
  return __int_as_float(__builtin_amdgcn_readlane(__float_as_int(v), lane));
}

template <int CTRL>
__device__ __forceinline__ float dppmov(float x) {
  return __int_as_float(
      __builtin_amdgcn_mov_dpp(__float_as_int(x), CTRL, 0xF, 0xF, true));
}

// lane-xor exchanges, all VALU (DPP), octet-safe:
__device__ __forceinline__ float xlane1(float x) { return dppmov<0xB1>(x); }  // quad_perm [1,0,3,2]
__device__ __forceinline__ float xlane2(float x) { return dppmov<0x4E>(x); }  // quad_perm [2,3,0,1]
// xor4 within octet = xor3 (quad_perm [3,2,1,0]) then xor7 (row_half_mirror)
__device__ __forceinline__ float xlane4(float x) { return dppmov<0x141>(dppmov<0x1B>(x)); }

// Packed fp32 FMA (VOP3P, arch-VGPR forced).
__device__ __forceinline__ void pkfma(float2& acc, const float2 w, const float2 h) {
  asm volatile("v_pk_fma_f32 %0, %1, %2, %0" : "+v"(acc) : "v"(w), "v"(h));
}

// LIGHT ballast: ONE dependent-chain FMA wave per CU (~1.6% VALU duty).
template <int BURST>
__device__ __forceinline__ void ballast_spin(const int* flag, int target, float seed,
                                             float* sink) {
  float x = seed;
  const float aa = 1.0000001f, bb = 1e-7f;
  while (__hip_atomic_load(flag, __ATOMIC_RELAXED, __HIP_MEMORY_SCOPE_AGENT) < target) {
#pragma unroll
    for (int q = 0; q < BURST; ++q) x = fmaf(x, aa, bb);
  }
  if (x == 12345.678f) *sink = x;   // unprovable -> loop not removable
}

// ---------------------------------------------------------------------------
// K1: pre[t][j] = Wih[row(j)] . x_t + bih + bhh
// Row permutation matches k_lstm lane j's owned row (R3-R5 proven):
//   r(j) = (g<<7) | dim,  g=(j>>1)&3, dim=((j>>3)<<1)|(j&1)   (bijective)
// ---------------------------------------------------------------------------
__global__ __launch_bounds__(512) void k_pre(
    const int* __restrict__ sentence, const float* __restrict__ embed,
    const float* __restrict__ Wih_f, const float* __restrict__ bih_f, const float* __restrict__ bhh_f,
    const float* __restrict__ Wih_b, const float* __restrict__ bih_b, const float* __restrict__ bhh_b,
    float* __restrict__ pre_f, float* __restrict__ pre_b)
{
  const int dir = blockIdx.x >> 8;
  const int t0 = (blockIdx.x & 255) * 32;
  const float* __restrict__ Wih = dir ? Wih_b : Wih_f;
  const float* __restrict__ bi  = dir ? bih_b : bih_f;
  const float* __restrict__ bh  = dir ? bhh_b : bhh_f;
  float* __restrict__ pre = dir ? pre_b : pre_f;
  const int j = threadIdx.x;
  const int r = (((j >> 1) & 3) << 7) | ((j >> 3) << 1) | (j & 1);
  float w[E_DIM];
  {
    const float2* w2 = (const float2*)(Wih + r * E_DIM);
#pragma unroll
    for (int q = 0; q < 25; ++q) { float2 v = w2[q]; w[2*q] = v.x; w[2*q+1] = v.y; }
  }
  const float bias = bi[r] + bh[r];
  __shared__ float xs[32][E_DIM];
  __shared__ int sidx[32];
  if (j < 32) sidx[j] = sentence[t0 + j];
  __syncthreads();
  for (int i = j; i < 32 * E_DIM; i += 512) {
    int tl = i / E_DIM;
    int e = i - tl * E_DIM;
    xs[tl][e] = embed[sidx[tl] * E_DIM + e];
  }
  __syncthreads();
  for (int tl = 0; tl < 32; ++tl) {
    float a0 = bias, a1 = 0.f;
#pragma unroll
    for (int e = 0; e < E_DIM; e += 2) {
      a0 += w[e]     * xs[tl][e];
      a1 += w[e + 1] * xs[tl][e + 1];
    }
    pre[(t0 + tl) * G4 + j] = a0 + a1;
  }
}

// ---------------------------------------------------------------------------
// K2: serial LSTM, 1 CU/dir — R8: R5 structure + 8-STEP VMEM BATCHING.
//
// Root cause (finally consistent with ALL rounds): hipcc emits
// `s_waitcnt vmcnt(0) lgkmcnt(0)` before every s_barrier (__syncthreads
// semantics). The step loop had 1 global pre-load + 1 global hcat-store
// between barriers -> EVERY step serially paid residual L3/HBM latency +
// store-ack at the barrier (~600-1000cy). This fixed cost is layout-
// invariant — exactly why R2/R3/R5 all measured ~1880cy/step regardless of
// LDS traffic or instruction count, and why "depth-2 prefetch" never
// helped (the drain killed it every step).
//
// R8: 8-step blocks. Issue 8 pre-loads for block B+1 at top of block B
// (pg[8] regs); buffer 8 hcat stores (hst[8]) and flush once per block.
// Only 1 barrier per 8 steps drains a VMEM roundtrip (8 pipelined loads
// ~= one latency); the other 7 drain only LDS (lgkm, ~30cy). All values
// bit-identical to R5 -> absmax stays 0.
// ---------------------------------------------------------------------------
__global__ __attribute__((amdgpu_flat_work_group_size(512, 512),
                          amdgpu_waves_per_eu(2, 2)))
void k_lstm(
    const float* __restrict__ Whh_f, const float* __restrict__ Whh_b,
    const float* __restrict__ h0, const float* __restrict__ c0,
    const float* __restrict__ pre_f, const float* __restrict__ pre_b,
    float* __restrict__ hcat, int* __restrict__ flag, float* __restrict__ sink)
{
  __shared__ float hbuf[2][HH];
  if (blockIdx.x >= 2) {
    if (threadIdx.x < 64)
      ballast_spin<512>(flag, 2, (float)(blockIdx.x * 64 + threadIdx.x), sink);
    return;
  }
  const int dir = blockIdx.x;
  const float* __restrict__ Whh = dir ? Whh_b : Whh_f;
  const float* __restrict__ pre = dir ? pre_b : pre_f;
  const int j = threadIdx.x;
  const int l = j & 7;               // lane-in-octet
  const int O = j >> 3;              // octet id (64) -> dims 2O, 2O+1
  const bool b0 = l & 1;             // item bit0 (dim parity ds)
  const bool b1 = (l >> 1) & 1;      // item bit1 (gate low bit)
  const bool b2 = (l >> 2) & 1;      // item bit2 (gate high bit)
  const int g = (l >> 1) & 3;        // this lane's final gate
  const int dim = (O << 1) | (l & 1);

  // wv[i*8 + 2k(+1)]: float2 halves of Whh[row(i)][chunk l+8k], row(i) =
  // ((i>>1)<<7) | (O<<1) | (i&1).  128 floats/thread.
  float2 wv[64];
#pragma unroll
  for (int i = 0; i < 8; ++i) {
    const int row = (((i >> 1) & 3) << 7) | (O << 1) | (i & 1);
    const float4* src = (const float4*)(Whh + row * HH);
#pragma unroll
    for (int k = 0; k < 4; ++k) {
      float4 v = src[l + 8 * k];
      wv[i * 8 + 2 * k]     = make_float2(v.x, v.y);
      wv[i * 8 + 2 * k + 1] = make_float2(v.z, v.w);
    }
  }
  // One-time pins (proven neutral; keeps loads hoisted out of the loop).
#define PIN8(B) asm volatile("" : "+v"(wv[B]), "+v"(wv[B+1]), "+v"(wv[B+2]), \
    "+v"(wv[B+3]), "+v"(wv[B+4]), "+v"(wv[B+5]), "+v"(wv[B+6]), "+v"(wv[B+7]))
  PIN8(0); PIN8(8); PIN8(16); PIN8(24); PIN8(32); PIN8(40); PIN8(48); PIN8(56);
#undef PIN8

  float c = c0[dir * HH + dim];
  if (g == 0) hbuf[0][dim] = h0[dir * HH + dim];
  __syncthreads();

#define TIX(s) (dir ? (T_LEN - 1 - (s)) : (s))
  float pf[8], pg[8], hst[8];
#pragma unroll
  for (int q = 0; q < 8; ++q) pf[q] = pre[TIX(q) * G4 + j];

  for (int sb = 0; sb < T_LEN; sb += 8) {
    const int nb = sb + 8;
    if (nb < T_LEN) {
#pragma unroll
      for (int q = 0; q < 8; ++q) pg[q] = pre[TIX(nb + q) * G4 + j];
    }
#pragma unroll
    for (int q = 0; q < 8; ++q) {
      const int s = sb + q;

      const float4* h4 = (const float4*)hbuf[s & 1];
      const float4 hc0 = h4[l];
      const float4 hc1 = h4[l + 8];
      const float4 hc2 = h4[l + 16];
      const float4 hc3 = h4[l + 24];
      const float2 h0a = make_float2(hc0.x, hc0.y), h0b = make_float2(hc0.z, hc0.w);
      const float2 h1a = make_float2(hc1.x, hc1.y), h1b = make_float2(hc1.z, hc1.w);
      const float2 h2a = make_float2(hc2.x, hc2.y), h2b = make_float2(hc2.z, hc2.w);
      const float2 h3a = make_float2(hc3.x, hc3.y), h3b = make_float2(hc3.z, hc3.w);

      float2 acc[8];
#pragma unroll
      for (int i = 0; i < 8; ++i) {
        acc[i] = make_float2(0.f, 0.f);
        pkfma(acc[i], wv[i * 8 + 0], h0a);
        pkfma(acc[i], wv[i * 8 + 1], h0b);
        pkfma(acc[i], wv[i * 8 + 2], h1a);
        pkfma(acc[i], wv[i * 8 + 3], h1b);
        pkfma(acc[i], wv[i * 8 + 4], h2a);
        pkfma(acc[i], wv[i * 8 + 5], h2b);
        pkfma(acc[i], wv[i * 8 + 6], h3a);
        pkfma(acc[i], wv[i * 8 + 7], h3b);
      }
      const float p0 = acc[0].x + acc[0].y;
      const float p1 = acc[1].x + acc[1].y;
      const float p2 = acc[2].x + acc[2].y;
      const float p3 = acc[3].x + acc[3].y;
      const float p4 = acc[4].x + acc[4].y;
      const float p5 = acc[5].x + acc[5].y;
      const float p6 = acc[6].x + acc[6].y;
      const float p7 = acc[7].x + acc[7].y;

      // reduce-scatter over octet: step1 xor4 (keep items with bit2==b2)
      const float u10 = b2 ? p4 : p0, v10 = b2 ? p0 : p4;
      const float u11 = b2 ? p5 : p1, v11 = b2 ? p1 : p5;
      const float u12 = b2 ? p6 : p2, v12 = b2 ? p2 : p6;
      const float u13 = b2 ? p7 : p3, v13 = b2 ? p3 : p7;
      const float q0 = u10 + xlane4(v10);
      const float q1 = u11 + xlane4(v11);
      const float q2 = u12 + xlane4(v12);
      const float q3 = u13 + xlane4(v13);
      // step2 xor2 (keep bit1==b1)
      const float u20 = b1 ? q2 : q0, v20 = b1 ? q0 : q2;
      const float u21 = b1 ? q3 : q1, v21 = b1 ? q1 : q3;
      const float r0 = u20 + xlane2(v20);
      const float r1 = u21 + xlane2(v21);
      // step3 xor1 (keep bit0==b0) -> full dot for row l
      const float u30 = b0 ? r1 : r0, v30 = b0 ? r0 : r1;
      const float dot = u30 + xlane1(v30);

      const float accv = dot + pf[q];

      const float sc = (g == 2) ? 2.0f : 1.0f;
      const float ev = __expf(-sc * accv);
      const float sg = 1.0f / (1.0f + ev);
      const float a  = (g == 2) ? (2.0f * sg - 1.0f) : sg;   // act of MY gate
      // gather the other 3 gates of my dim (lanes l^2, l^4, l^6)
      const float s2v = xlane2(a);   // gate g^1
      const float s4v = xlane4(a);   // gate g^2
      const float s6v = xlane2(s4v); // gate g^3
      // value of gate G sits at xor-distance (g^G)<<1: select by g
      const float iv  = b2 ? (b1 ? s6v : s4v) : (b1 ? s2v : a);
      const float fv  = b2 ? (b1 ? s4v : s6v) : (b1 ? a   : s2v);
      const float gv  = b2 ? (b1 ? s2v : a  ) : (b1 ? s6v : s4v);
      const float ovv = b2 ? (b1 ? a   : s2v) : (b1 ? s4v : s6v);
      c = fv * c + iv * gv;
      const float e2 = __expf(-2.0f * c);
      const float th = 2.0f / (1.0f + e2) - 1.0f;
      const float h = ovv * th;
      if (g == 0) {
        hbuf[(s + 1) & 1][dim] = h;            // LDS double-buffer (per step)
        hst[q] = h;                            // global store BUFFERED
      }
      __syncthreads();
    }
    // flush 8 hcat stores once per block (drained at next block's 1st barrier)
    if (g == 0) {
#pragma unroll
      for (int q = 0; q < 8; ++q)
        hcat[TIX(sb + q) * (2 * HH) + dir * HH + dim] = hst[q];
    }
    if (nb < T_LEN) {
#pragma unroll
      for (int q = 0; q < 8; ++q) pf[q] = pg[q];
    }
  }
#undef TIX
  if (j == 0) atomicAdd(flag, 1);            // release ballast
}

// ---------------------------------------------------------------------------
// K3: feats32[t][k] = W_out[k] . hcat[t] + b_out[k]   (stride-32 layout)
// ---------------------------------------------------------------------------
__global__ __launch_bounds__(256) void k_feats(
    const float* __restrict__ hcat, const float* __restrict__ Wout,
    const float* __restrict__ bout, float* __restrict__ feats32)
{
  const int t0 = blockIdx.x * 32;
  __shared__ float hsh[32 * 257];
  __shared__ float wsh[KT * 256];
  __shared__ float bsh[KT];
  const int tid = threadIdx.x;
  for (int i = tid; i < 32 * 256; i += 256) {
    int tl = i >> 8, dd = i & 255;
    hsh[tl * 257 + dd] = hcat[(t0 + tl) * 256 + dd];
  }
  for (int i = tid; i < KT * 256; i += 256) wsh[i] = Wout[i];
  if (tid < KT) bsh[tid] = bout[tid];
  __syncthreads();
  for (int idx = tid; idx < 32 * KT; idx += 256) {
    int tl = idx & 31, k = idx >> 5;
    float a0 = bsh[k], a1 = 0.f, a2 = 0.f, a3 = 0.f;
#pragma unroll 8
    for (int dd = 0; dd < 256; dd += 4) {
      a0 += hsh[tl * 257 + dd + 0] * wsh[k * 256 + dd + 0];
      a1 += hsh[tl * 257 + dd + 1] * wsh[k * 256 + dd + 1];
      a2 += hsh[tl * 257 + dd + 2] * wsh[k * 256 + dd + 2];
      a3 += hsh[tl * 257 + dd + 3] * wsh[k * 256 + dd + 3];
    }
    feats32[(t0 + tl) * 32 + k] = ((a0 + a1) + (a2 + a3));
  }
}

// ---------------------------------------------------------------------------
// K4: sequential Viterbi forward (hit chain bound w/ ballast).
// ---------------------------------------------------------------------------
__global__ __launch_bounds__(64) void k_vit_fwd(
    const float* __restrict__ feats32, const float* __restrict__ trans,
    float* __restrict__ fvstore, float* __restrict__ out, int* __restrict__ misc,
    int* __restrict__ flag, float* __restrict__ sink)
{
  if (blockIdx.x >= 1) {
    ballast_spin<256>(flag, 1, (float)(blockIdx.x * 64 + threadIdx.x), sink);
    return;
  }
  const int j = threadIdx.x;
  const int j32 = j & 31;
  float trow[KT];
#pragma unroll
  for (int i = 0; i < KT; ++i)
    trow[i] = (j < KT) ? ((j == START_T || i == STOP_T) ? NEGV : trans[j * KT + i]) : NEGV;
  float fvn = (j == START_T) ? 0.0f : NEGV;
  float pf[8];
#pragma unroll
  for (int q = 0; q < 8; ++q) pf[q] = feats32[q * 32 + j32];

#define MAX3(a,b,cc) fmaxf(fmaxf((a),(b)),(cc))
#define CAND(i) (rl(fvn, (i)) + trow[(i)])

  for (int tb = 0; tb < T_LEN; tb += 8) {
#pragma unroll
    for (int q = 0; q < 8; ++q) {
      const int t = tb + q;
      fvstore[t * 64 + j] = fvn;                  // off-chain, all lanes
      float m0 = MAX3(CAND(0),  CAND(1),  CAND(2));
      float m1 = MAX3(CAND(3),  CAND(4),  CAND(5));
      float m2 = MAX3(CAND(6),  CAND(7),  CAND(8));
      float m3 = MAX3(CAND(9),  CAND(10), CAND(11));
      float m4 = MAX3(CAND(12), CAND(13), CAND(14));
      float m5 = MAX3(CAND(15), CAND(16), CAND(17));
      float m6 = MAX3(CAND(18), CAND(19), CAND(20));
      float m7 = fmaxf(CAND(21), CAND(22));
      float n0 = MAX3(m0, m1, m2);
      float n1 = MAX3(m3, m4, m5);
      float n2 = fmaxf(m6, m7);
      const float best = MAX3(n0, n1, n2);        // exact max: order-free
      fvn = best + pf[q];
      const int tpf = t + 8;
      const int tc = (tpf < T_LEN) ? tpf : (T_LEN - 1);
      pf[q] = feats32[tc * 32 + j32];             // unconditional
    }
  }
  const float trS = (j < KT) ? ((j == STOP_T) ? NEGV : trans[STOP_T * KT + j]) : 0.0f;
  float term = (j < KT) ? (fvn + trS) : -3.0e38f;
  int idx = (j < KT) ? j : 63;
#pragma unroll
  for (int off = 16; off >= 1; off >>= 1) {
    float ovl = __shfl_xor(term, off);
    int oi = __shfl_xor(idx, off);
    if (ovl > term || (ovl == term && oi < idx)) { term = ovl; idx = oi; }
  }
  if (j == 0) { out[0] = term; misc[0] = idx; atomicAdd(flag, 1); }
}

// ---------------------------------------------------------------------------
// K4b: parallel backpointers from stored fv (bitwise-identical candidates,
// strict-> first-max == jnp.argmax).
// ---------------------------------------------------------------------------
__global__ __launch_bounds__(256) void k_bptr(
    const float* __restrict__ fvstore, const float* __restrict__ trans,
    unsigned char* __restrict__ bptr)
{
  const int t0 = blockIdx.x * 32;
  __shared__ float fv[32 * 24];
  __shared__ float trc[KT * KT];
  const int tid = threadIdx.x;
  for (int i = tid; i < 32 * 24; i += 256) {
    int tl = i / 24, e = i - tl * 24;
    fv[i] = fvstore[(t0 + tl) * 64 + e];
  }
  for (int i = tid; i < KT * KT; i += 256) {
    int jj = i / KT, ii = i - jj * KT;
    trc[i] = (jj == START_T || ii == STOP_T) ? NEGV : trans[i];
  }
  __syncthreads();
  for (int p = tid; p < 32 * KT; p += 256) {
    int tl = p / KT, jj = p - tl * KT;
    const float* fvr = fv + tl * 24;
    const float* tr = trc + jj * KT;
    float best = fvr[0] + tr[0]; int bi = 0;
#pragma unroll
    for (int i = 1; i < KT; ++i) {
      float v = fvr[i] + tr[i];
      if (v > best) { best = v; bi = i; }
    }
    bptr[(t0 + tl) * KT + jj] = (unsigned char)bi;
  }
}

// ---------------------------------------------------------------------------
// K5: compose 32-step backpointer maps per chunk (parallel).
// ---------------------------------------------------------------------------
__global__ __launch_bounds__(64) void k_compose(
    const unsigned char* __restrict__ bptr, unsigned char* __restrict__ maps)
{
  const int c = blockIdx.x;
  const int lo = c * 32;
  __shared__ unsigned char rows[32 * 24];
  const int tid = threadIdx.x;
  for (int i = tid; i < 32 * KT; i += 64) {
    int tl = i / KT, e = i - tl * KT;
    rows[tl * 24 + e] = bptr[(lo + tl) * KT + e];
  }
  __syncthreads();
  if (tid < KT) {
    int x = tid;
    for (int tl = 31; tl >= 0; --tl) x = rows[tl * 24 + x];
    maps[c * KT + tid] = (unsigned char)x;
  }
}

// K6: sequential scan over 256 chunk maps.
__global__ __launch_bounds__(64) void k_backscan(
    const unsigned char* __restrict__ maps, const int* __restrict__ misc,
    int* __restrict__ btags)
{
  __shared__ unsigned char msh[256 * KT];
  const int tid = threadIdx.x;
  for (int i = tid; i < 256 * KT; i += 64) msh[i] = maps[i];
  __syncthreads();
  if (tid == 0) {
    int e = misc[0];
    for (int c = 255; c >= 0; --c) { btags[c] = e; e = msh[c * KT + e]; }
  }
}

// K7: evaluate interior path per chunk (parallel), write tags as floats.
__global__ __launch_bounds__(64) void k_backeval(
    const unsigned char* __restrict__ bptr, const int* __restrict__ btags,
    float* __restrict__ out)
{
  const int c = blockIdx.x;
  const int lo = c * 32;
  __shared__ unsigned char rows[32 * 24];
  __shared__ int tags[32];
  const int tid = threadIdx.x;
  for (int i = tid; i < 32 * KT; i += 64) {
    int tl = i / KT, e = i - tl * KT;
    rows[tl * 24 + e] = bptr[(lo + tl) * KT + e];
  }
  __syncthreads();
  if (tid == 0) {
    int tg = btags[c];
    tags[31] = tg;
    for (int tl = 31; tl >= 1; --tl) { tg = rows[tl * 24 + tg]; tags[tl - 1] = tg; }
  }
  __syncthreads();
  if (tid < 32) out[1 + lo + tid] = (float)tags[tid];
}

// ---------------------------------------------------------------------------
extern "C" void kernel_launch(void* const* d_in, const int* in_sizes, int n_in,
                              void* d_out, int out_size, void* d_ws, size_t ws_size,
                              hipStream_t stream) {
  const int*   sentence = (const int*)d_in[0];
  const float* embed    = (const float*)d_in[1];
  const float* Wih_f    = (const float*)d_in[2];
  const float* Whh_f    = (const float*)d_in[3];
  const float* bih_f    = (const float*)d_in[4];
  const float* bhh_f    = (const float*)d_in[5];
  const float* Wih_b    = (const float*)d_in[6];
  const float* Whh_b    = (const float*)d_in[7];
  const float* bih_b    = (const float*)d_in[8];
  const float* bhh_b    = (const float*)d_in[9];
  const float* Wout     = (const float*)d_in[10];
  const float* bout     = (const float*)d_in[11];
  const float* trans    = (const float*)d_in[12];
  const float* h0       = (const float*)d_in[13];
  const float* c0       = (const float*)d_in[14];
  float* out = (float*)d_out;

  float* ws = (float*)d_ws;
  float* pre_f = ws;                               // [T][512]
  float* pre_b = pre_f + (size_t)T_LEN * G4;       // [T][512]
  float* hcat  = pre_b + (size_t)T_LEN * G4;       // [T][256]
  float* feats32 = hcat + (size_t)T_LEN * 2 * HH;  // [T][32]
  unsigned char* bptr = (unsigned char*)(feats32 + (size_t)T_LEN * 32);
  unsigned char* maps = bptr + (size_t)T_LEN * KT;
  int* btags = (int*)(maps + 256 * KT);
  int* misc  = btags + 256;
  int* flags = misc + 8;                           // [0]=lstm done, [1]=vit done
  float* sink = (float*)(flags + 8);
  float* fvstore = pre_f;                          // [T][64], pre dead after k_lstm

  hipMemsetAsync(flags, 0, 8 * sizeof(int), stream);
  k_pre<<<512, 512, 0, stream>>>(sentence, embed, Wih_f, bih_f, bhh_f,
                                 Wih_b, bih_b, bhh_b, pre_f, pre_b);
  k_lstm<<<256, 512, 0, stream>>>(Whh_f, Whh_b, h0, c0, pre_f, pre_b, hcat,
                                  flags + 0, sink);
  k_feats<<<256, 256, 0, stream>>>(hcat, Wout, bout, feats32);
  k_vit_fwd<<<256, 64, 0, stream>>>(feats32, trans, fvstore, out, misc,
                                    flags + 1, sink);
  k_bptr<<<256, 256, 0, stream>>>(fvstore, trans, bptr);
  k_compose<<<256, 64, 0, stream>>>(bptr, maps);
  k_backscan<<<1, 64, 0, stream>>>(maps, misc, btags);
  k_backeval<<<256, 64, 0, stream>>>(bptr, btags, out);
}

// Round 9
// 6430.199 us; speedup vs baseline: 11.0065x; 1.0884x over previous
//
#include <hip/hip_runtime.h>

#define T_LEN 8192
#define HH 128
#define G4 512
#define E_DIM 50
#define KT 23
#define START_T 21
#define STOP_T 22
#define NEGV -10000.0f

__device__ __forceinline__ float rl(float v, int lane) {
  return __int_as_float(__builtin_amdgcn_readlane(__float_as_int(v), lane));
}

template <int CTRL>
__device__ __forceinline__ float dppmov(float x) {
  return __int_as_float(
      __builtin_amdgcn_mov_dpp(__float_as_int(x), CTRL, 0xF, 0xF, true));
}

// lane-xor exchanges, all VALU (DPP), octet-safe:
__device__ __forceinline__ float xlane1(float x) { return dppmov<0xB1>(x); }  // quad_perm [1,0,3,2]
__device__ __forceinline__ float xlane2(float x) { return dppmov<0x4E>(x); }  // quad_perm [2,3,0,1]
// xor4 within octet = xor3 (quad_perm [3,2,1,0]) then xor7 (row_half_mirror)
__device__ __forceinline__ float xlane4(float x) { return dppmov<0x141>(dppmov<0x1B>(x)); }

// Plain-C packed-equivalent FMA: bit-identical per component to v_pk_fma_f32,
// but WITHOUT an arch-VGPR ("v") constraint — lets the compiler source the
// AGPR-parked weights DIRECTLY (gfx90a+/gfx950 VALU can read AGPRs; LLVM AV_*
// operand classes). R1-R8's inline-asm "v" constraint was forcing a
// v_accvgpr_read copy before EVERY use (~128/thread/step) — self-inflicted.
__device__ __forceinline__ void cfma(float2& acc, const float2 w, const float2 h) {
  acc.x = fmaf(w.x, h.x, acc.x);
  acc.y = fmaf(w.y, h.y, acc.y);
}

// LIGHT ballast: ONE dependent-chain FMA wave per CU (~1.6% VALU duty).
template <int BURST>
__device__ __forceinline__ void ballast_spin(const int* flag, int target, float seed,
                                             float* sink) {
  float x = seed;
  const float aa = 1.0000001f, bb = 1e-7f;
  while (__hip_atomic_load(flag, __ATOMIC_RELAXED, __HIP_MEMORY_SCOPE_AGENT) < target) {
#pragma unroll
    for (int q = 0; q < BURST; ++q) x = fmaf(x, aa, bb);
  }
  if (x == 12345.678f) *sink = x;   // unprovable -> loop not removable
}

// ---------------------------------------------------------------------------
// K1: pre[t][j] = Wih[row(j)] . x_t + bih + bhh
// Row permutation matches k_lstm lane j's owned row (R3-R8 proven):
//   r(j) = (g<<7) | dim,  g=(j>>1)&3, dim=((j>>3)<<1)|(j&1)   (bijective)
// ---------------------------------------------------------------------------
__global__ __launch_bounds__(512) void k_pre(
    const int* __restrict__ sentence, const float* __restrict__ embed,
    const float* __restrict__ Wih_f, const float* __restrict__ bih_f, const float* __restrict__ bhh_f,
    const float* __restrict__ Wih_b, const float* __restrict__ bih_b, const float* __restrict__ bhh_b,
    float* __restrict__ pre_f, float* __restrict__ pre_b)
{
  const int dir = blockIdx.x >> 8;
  const int t0 = (blockIdx.x & 255) * 32;
  const float* __restrict__ Wih = dir ? Wih_b : Wih_f;
  const float* __restrict__ bi  = dir ? bih_b : bih_f;
  const float* __restrict__ bh  = dir ? bhh_b : bhh_f;
  float* __restrict__ pre = dir ? pre_b : pre_f;
  const int j = threadIdx.x;
  const int r = (((j >> 1) & 3) << 7) | ((j >> 3) << 1) | (j & 1);
  float w[E_DIM];
  {
    const float2* w2 = (const float2*)(Wih + r * E_DIM);
#pragma unroll
    for (int q = 0; q < 25; ++q) { float2 v = w2[q]; w[2*q] = v.x; w[2*q+1] = v.y; }
  }
  const float bias = bi[r] + bh[r];
  __shared__ float xs[32][E_DIM];
  __shared__ int sidx[32];
  if (j < 32) sidx[j] = sentence[t0 + j];
  __syncthreads();
  for (int i = j; i < 32 * E_DIM; i += 512) {
    int tl = i / E_DIM;
    int e = i - tl * E_DIM;
    xs[tl][e] = embed[sidx[tl] * E_DIM + e];
  }
  __syncthreads();
  for (int tl = 0; tl < 32; ++tl) {
    float a0 = bias, a1 = 0.f;
#pragma unroll
    for (int e = 0; e < E_DIM; e += 2) {
      a0 += w[e]     * xs[tl][e];
      a1 += w[e + 1] * xs[tl][e + 1];
    }
    pre[(t0 + tl) * G4 + j] = a0 + a1;
  }
}

// ---------------------------------------------------------------------------
// K2: serial LSTM, 1 CU/dir — R9: R8 structure, plain-C MACs (no "v" force).
//
// R8 (8-step VMEM batching) won 180cy/step (drain was L3-residual, ~200cy).
// Remaining 1709cy/step vs ~500cy floor. R9 removes the copy tax at its
// actual source: the pkfma inline asm's "v" constraints forced
// v_accvgpr_read of each AGPR-parked weight before EVERY use
// (~128 copies/thread/step ~= 512cy/SIMD). Plain fmaf lets the backend
// allocate AV classes and source AGPRs directly in the FMA. Numerics
// bit-identical (fma per component == v_pk_fma_f32 per component).
// ---------------------------------------------------------------------------
__global__ __attribute__((amdgpu_flat_work_group_size(512, 512),
                          amdgpu_waves_per_eu(2, 2)))
void k_lstm(
    const float* __restrict__ Whh_f, const float* __restrict__ Whh_b,
    const float* __restrict__ h0, const float* __restrict__ c0,
    const float* __restrict__ pre_f, const float* __restrict__ pre_b,
    float* __restrict__ hcat, int* __restrict__ flag, float* __restrict__ sink)
{
  __shared__ float hbuf[2][HH];
  if (blockIdx.x >= 2) {
    if (threadIdx.x < 64)
      ballast_spin<512>(flag, 2, (float)(blockIdx.x * 64 + threadIdx.x), sink);
    return;
  }
  const int dir = blockIdx.x;
  const float* __restrict__ Whh = dir ? Whh_b : Whh_f;
  const float* __restrict__ pre = dir ? pre_b : pre_f;
  const int j = threadIdx.x;
  const int l = j & 7;               // lane-in-octet
  const int O = j >> 3;              // octet id (64) -> dims 2O, 2O+1
  const bool b0 = l & 1;             // item bit0 (dim parity ds)
  const bool b1 = (l >> 1) & 1;      // item bit1 (gate low bit)
  const bool b2 = (l >> 2) & 1;      // item bit2 (gate high bit)
  const int g = (l >> 1) & 3;        // this lane's final gate
  const int dim = (O << 1) | (l & 1);

  // wv[i*8 + 2k(+1)]: float2 halves of Whh[row(i)][chunk l+8k], row(i) =
  // ((i>>1)<<7) | (O<<1) | (i&1).  128 floats/thread.
  float2 wv[64];
#pragma unroll
  for (int i = 0; i < 8; ++i) {
    const int row = (((i >> 1) & 3) << 7) | (O << 1) | (i & 1);
    const float4* src = (const float4*)(Whh + row * HH);
#pragma unroll
    for (int k = 0; k < 4; ++k) {
      float4 v = src[l + 8 * k];
      wv[i * 8 + 2 * k]     = make_float2(v.x, v.y);
      wv[i * 8 + 2 * k + 1] = make_float2(v.z, v.w);
    }
  }
  // One-time pins (proven neutral; keep loads hoisted/completed pre-loop).
#define PIN8(B) asm volatile("" : "+v"(wv[B]), "+v"(wv[B+1]), "+v"(wv[B+2]), \
    "+v"(wv[B+3]), "+v"(wv[B+4]), "+v"(wv[B+5]), "+v"(wv[B+6]), "+v"(wv[B+7]))
  PIN8(0); PIN8(8); PIN8(16); PIN8(24); PIN8(32); PIN8(40); PIN8(48); PIN8(56);
#undef PIN8

  float c = c0[dir * HH + dim];
  if (g == 0) hbuf[0][dim] = h0[dir * HH + dim];
  __syncthreads();

#define TIX(s) (dir ? (T_LEN - 1 - (s)) : (s))
  float pf[8], pg[8], hst[8];
#pragma unroll
  for (int q = 0; q < 8; ++q) pf[q] = pre[TIX(q) * G4 + j];

  for (int sb = 0; sb < T_LEN; sb += 8) {
    const int nb = sb + 8;
    if (nb < T_LEN) {
#pragma unroll
      for (int q = 0; q < 8; ++q) pg[q] = pre[TIX(nb + q) * G4 + j];
    }
#pragma unroll
    for (int q = 0; q < 8; ++q) {
      const int s = sb + q;

      const float4* h4 = (const float4*)hbuf[s & 1];
      const float4 hc0 = h4[l];
      const float4 hc1 = h4[l + 8];
      const float4 hc2 = h4[l + 16];
      const float4 hc3 = h4[l + 24];
      const float2 h0a = make_float2(hc0.x, hc0.y), h0b = make_float2(hc0.z, hc0.w);
      const float2 h1a = make_float2(hc1.x, hc1.y), h1b = make_float2(hc1.z, hc1.w);
      const float2 h2a = make_float2(hc2.x, hc2.y), h2b = make_float2(hc2.z, hc2.w);
      const float2 h3a = make_float2(hc3.x, hc3.y), h3b = make_float2(hc3.z, hc3.w);

      float2 acc[8];
#pragma unroll
      for (int i = 0; i < 8; ++i) {
        acc[i] = make_float2(0.f, 0.f);
        cfma(acc[i], wv[i * 8 + 0], h0a);
        cfma(acc[i], wv[i * 8 + 1], h0b);
        cfma(acc[i], wv[i * 8 + 2], h1a);
        cfma(acc[i], wv[i * 8 + 3], h1b);
        cfma(acc[i], wv[i * 8 + 4], h2a);
        cfma(acc[i], wv[i * 8 + 5], h2b);
        cfma(acc[i], wv[i * 8 + 6], h3a);
        cfma(acc[i], wv[i * 8 + 7], h3b);
      }
      const float p0 = acc[0].x + acc[0].y;
      const float p1 = acc[1].x + acc[1].y;
      const float p2 = acc[2].x + acc[2].y;
      const float p3 = acc[3].x + acc[3].y;
      const float p4 = acc[4].x + acc[4].y;
      const float p5 = acc[5].x + acc[5].y;
      const float p6 = acc[6].x + acc[6].y;
      const float p7 = acc[7].x + acc[7].y;

      // reduce-scatter over octet: step1 xor4 (keep items with bit2==b2)
      const float u10 = b2 ? p4 : p0, v10 = b2 ? p0 : p4;
      const float u11 = b2 ? p5 : p1, v11 = b2 ? p1 : p5;
      const float u12 = b2 ? p6 : p2, v12 = b2 ? p2 : p6;
      const float u13 = b2 ? p7 : p3, v13 = b2 ? p3 : p7;
      const float q0 = u10 + xlane4(v10);
      const float q1 = u11 + xlane4(v11);
      const float q2 = u12 + xlane4(v12);
      const float q3 = u13 + xlane4(v13);
      // step2 xor2 (keep bit1==b1)
      const float u20 = b1 ? q2 : q0, v20 = b1 ? q0 : q2;
      const float u21 = b1 ? q3 : q1, v21 = b1 ? q1 : q3;
      const float r0 = u20 + xlane2(v20);
      const float r1 = u21 + xlane2(v21);
      // step3 xor1 (keep bit0==b0) -> full dot for row l
      const float u30 = b0 ? r1 : r0, v30 = b0 ? r0 : r1;
      const float dot = u30 + xlane1(v30);

      const float accv = dot + pf[q];

      const float sc = (g == 2) ? 2.0f : 1.0f;
      const float ev = __expf(-sc * accv);
      const float sg = 1.0f / (1.0f + ev);
      const float a  = (g == 2) ? (2.0f * sg - 1.0f) : sg;   // act of MY gate
      // gather the other 3 gates of my dim (lanes l^2, l^4, l^6)
      const float s2v = xlane2(a);   // gate g^1
      const float s4v = xlane4(a);   // gate g^2
      const float s6v = xlane2(s4v); // gate g^3
      // value of gate G sits at xor-distance (g^G)<<1: select by g
      const float iv  = b2 ? (b1 ? s6v : s4v) : (b1 ? s2v : a);
      const float fv  = b2 ? (b1 ? s4v : s6v) : (b1 ? a   : s2v);
      const float gv  = b2 ? (b1 ? s2v : a  ) : (b1 ? s6v : s4v);
      const float ovv = b2 ? (b1 ? a   : s2v) : (b1 ? s4v : s6v);
      c = fv * c + iv * gv;
      const float e2 = __expf(-2.0f * c);
      const float th = 2.0f / (1.0f + e2) - 1.0f;
      const float h = ovv * th;
      if (g == 0) {
        hbuf[(s + 1) & 1][dim] = h;            // LDS double-buffer (per step)
        hst[q] = h;                            // global store BUFFERED
      }
      __syncthreads();
    }
    // flush 8 hcat stores once per block (drained at next block's 1st barrier)
    if (g == 0) {
#pragma unroll
      for (int q = 0; q < 8; ++q)
        hcat[TIX(sb + q) * (2 * HH) + dir * HH + dim] = hst[q];
    }
    if (nb < T_LEN) {
#pragma unroll
      for (int q = 0; q < 8; ++q) pf[q] = pg[q];
    }
  }
#undef TIX
  if (j == 0) atomicAdd(flag, 1);            // release ballast
}

// ---------------------------------------------------------------------------
// K3: feats32[t][k] = W_out[k] . hcat[t] + b_out[k]   (stride-32 layout)
// ---------------------------------------------------------------------------
__global__ __launch_bounds__(256) void k_feats(
    const float* __restrict__ hcat, const float* __restrict__ Wout,
    const float* __restrict__ bout, float* __restrict__ feats32)
{
  const int t0 = blockIdx.x * 32;
  __shared__ float hsh[32 * 257];
  __shared__ float wsh[KT * 256];
  __shared__ float bsh[KT];
  const int tid = threadIdx.x;
  for (int i = tid; i < 32 * 256; i += 256) {
    int tl = i >> 8, dd = i & 255;
    hsh[tl * 257 + dd] = hcat[(t0 + tl) * 256 + dd];
  }
  for (int i = tid; i < KT * 256; i += 256) wsh[i] = Wout[i];
  if (tid < KT) bsh[tid] = bout[tid];
  __syncthreads();
  for (int idx = tid; idx < 32 * KT; idx += 256) {
    int tl = idx & 31, k = idx >> 5;
    float a0 = bsh[k], a1 = 0.f, a2 = 0.f, a3 = 0.f;
#pragma unroll 8
    for (int dd = 0; dd < 256; dd += 4) {
      a0 += hsh[tl * 257 + dd + 0] * wsh[k * 256 + dd + 0];
      a1 += hsh[tl * 257 + dd + 1] * wsh[k * 256 + dd + 1];
      a2 += hsh[tl * 257 + dd + 2] * wsh[k * 256 + dd + 2];
      a3 += hsh[tl * 257 + dd + 3] * wsh[k * 256 + dd + 3];
    }
    feats32[(t0 + tl) * 32 + k] = ((a0 + a1) + (a2 + a3));
  }
}

// ---------------------------------------------------------------------------
// K4: sequential Viterbi forward (hit chain bound w/ ballast).
// ---------------------------------------------------------------------------
__global__ __launch_bounds__(64) void k_vit_fwd(
    const float* __restrict__ feats32, const float* __restrict__ trans,
    float* __restrict__ fvstore, float* __restrict__ out, int* __restrict__ misc,
    int* __restrict__ flag, float* __restrict__ sink)
{
  if (blockIdx.x >= 1) {
    ballast_spin<256>(flag, 1, (float)(blockIdx.x * 64 + threadIdx.x), sink);
    return;
  }
  const int j = threadIdx.x;
  const int j32 = j & 31;
  float trow[KT];
#pragma unroll
  for (int i = 0; i < KT; ++i)
    trow[i] = (j < KT) ? ((j == START_T || i == STOP_T) ? NEGV : trans[j * KT + i]) : NEGV;
  float fvn = (j == START_T) ? 0.0f : NEGV;
  float pf[8];
#pragma unroll
  for (int q = 0; q < 8; ++q) pf[q] = feats32[q * 32 + j32];

#define MAX3(a,b,cc) fmaxf(fmaxf((a),(b)),(cc))
#define CAND(i) (rl(fvn, (i)) + trow[(i)])

  for (int tb = 0; tb < T_LEN; tb += 8) {
#pragma unroll
    for (int q = 0; q < 8; ++q) {
      const int t = tb + q;
      fvstore[t * 64 + j] = fvn;                  // off-chain, all lanes
      float m0 = MAX3(CAND(0),  CAND(1),  CAND(2));
      float m1 = MAX3(CAND(3),  CAND(4),  CAND(5));
      float m2 = MAX3(CAND(6),  CAND(7),  CAND(8));
      float m3 = MAX3(CAND(9),  CAND(10), CAND(11));
      float m4 = MAX3(CAND(12), CAND(13), CAND(14));
      float m5 = MAX3(CAND(15), CAND(16), CAND(17));
      float m6 = MAX3(CAND(18), CAND(19), CAND(20));
      float m7 = fmaxf(CAND(21), CAND(22));
      float n0 = MAX3(m0, m1, m2);
      float n1 = MAX3(m3, m4, m5);
      float n2 = fmaxf(m6, m7);
      const float best = MAX3(n0, n1, n2);        // exact max: order-free
      fvn = best + pf[q];
      const int tpf = t + 8;
      const int tc = (tpf < T_LEN) ? tpf : (T_LEN - 1);
      pf[q] = feats32[tc * 32 + j32];             // unconditional
    }
  }
  const float trS = (j < KT) ? ((j == STOP_T) ? NEGV : trans[STOP_T * KT + j]) : 0.0f;
  float term = (j < KT) ? (fvn + trS) : -3.0e38f;
  int idx = (j < KT) ? j : 63;
#pragma unroll
  for (int off = 16; off >= 1; off >>= 1) {
    float ovl = __shfl_xor(term, off);
    int oi = __shfl_xor(idx, off);
    if (ovl > term || (ovl == term && oi < idx)) { term = ovl; idx = oi; }
  }
  if (j == 0) { out[0] = term; misc[0] = idx; atomicAdd(flag, 1); }
}

// ---------------------------------------------------------------------------
// K4b: parallel backpointers from stored fv (bitwise-identical candidates,
// strict-> first-max == jnp.argmax).
// ---------------------------------------------------------------------------
__global__ __launch_bounds__(256) void k_bptr(
    const float* __restrict__ fvstore, const float* __restrict__ trans,
    unsigned char* __restrict__ bptr)
{
  const int t0 = blockIdx.x * 32;
  __shared__ float fv[32 * 24];
  __shared__ float trc[KT * KT];
  const int tid = threadIdx.x;
  for (int i = tid; i < 32 * 24; i += 256) {
    int tl = i / 24, e = i - tl * 24;
    fv[i] = fvstore[(t0 + tl) * 64 + e];
  }
  for (int i = tid; i < KT * KT; i += 256) {
    int jj = i / KT, ii = i - jj * KT;
    trc[i] = (jj == START_T || ii == STOP_T) ? NEGV : trans[i];
  }
  __syncthreads();
  for (int p = tid; p < 32 * KT; p += 256) {
    int tl = p / KT, jj = p - tl * KT;
    const float* fvr = fv + tl * 24;
    const float* tr = trc + jj * KT;
    float best = fvr[0] + tr[0]; int bi = 0;
#pragma unroll
    for (int i = 1; i < KT; ++i) {
      float v = fvr[i] + tr[i];
      if (v > best) { best = v; bi = i; }
    }
    bptr[(t0 + tl) * KT + jj] = (unsigned char)bi;
  }
}

// ---------------------------------------------------------------------------
// K5: compose 32-step backpointer maps per chunk (parallel).
// ---------------------------------------------------------------------------
__global__ __launch_bounds__(64) void k_compose(
    const unsigned char* __restrict__ bptr, unsigned char* __restrict__ maps)
{
  const int c = blockIdx.x;
  const int lo = c * 32;
  __shared__ unsigned char rows[32 * 24];
  const int tid = threadIdx.x;
  for (int i = tid; i < 32 * KT; i += 64) {
    int tl = i / KT, e = i - tl * KT;
    rows[tl * 24 + e] = bptr[(lo + tl) * KT + e];
  }
  __syncthreads();
  if (tid < KT) {
    int x = tid;
    for (int tl = 31; tl >= 0; --tl) x = rows[tl * 24 + x];
    maps[c * KT + tid] = (unsigned char)x;
  }
}

// K6: sequential scan over 256 chunk maps.
__global__ __launch_bounds__(64) void k_backscan(
    const unsigned char* __restrict__ maps, const int* __restrict__ misc,
    int* __restrict__ btags)
{
  __shared__ unsigned char msh[256 * KT];
  const int tid = threadIdx.x;
  for (int i = tid; i < 256 * KT; i += 64) msh[i] = maps[i];
  __syncthreads();
  if (tid == 0) {
    int e = misc[0];
    for (int c = 255; c >= 0; --c) { btags[c] = e; e = msh[c * KT + e]; }
  }
}

// K7: evaluate interior path per chunk (parallel), write tags as floats.
__global__ __launch_bounds__(64) void k_backeval(
    const unsigned char* __restrict__ bptr, const int* __restrict__ btags,
    float* __restrict__ out)
{
  const int c = blockIdx.x;
  const int lo = c * 32;
  __shared__ unsigned char rows[32 * 24];
  __shared__ int tags[32];
  const int tid = threadIdx.x;
  for (int i = tid; i < 32 * KT; i += 64) {
    int tl = i / KT, e = i - tl * KT;
    rows[tl * 24 + e] = bptr[(lo + tl) * KT + e];
  }
  __syncthreads();
  if (tid == 0) {
    int tg = btags[c];
    tags[31] = tg;
    for (int tl = 31; tl >= 1; --tl) { tg = rows[tl * 24 + tg]; tags[tl - 1] = tg; }
  }
  __syncthreads();
  if (tid < 32) out[1 + lo + tid] = (float)tags[tid];
}

// ---------------------------------------------------------------------------
extern "C" void kernel_launch(void* const* d_in, const int* in_sizes, int n_in,
                              void* d_out, int out_size, void* d_ws, size_t ws_size,
                              hipStream_t stream) {
  const int*   sentence = (const int*)d_in[0];
  const float* embed    = (const float*)d_in[1];
  const float* Wih_f    = (const float*)d_in[2];
  const float* Whh_f    = (const float*)d_in[3];
  const float* bih_f    = (const float*)d_in[4];
  const float* bhh_f    = (const float*)d_in[5];
  const float* Wih_b    = (const float*)d_in[6];
  const float* Whh_b    = (const float*)d_in[7];
  const float* bih_b    = (const float*)d_in[8];
  const float* bhh_b    = (const float*)d_in[9];
  const float* Wout     = (const float*)d_in[10];
  const float* bout     = (const float*)d_in[11];
  const float* trans    = (const float*)d_in[12];
  const float* h0       = (const float*)d_in[13];
  const float* c0       = (const float*)d_in[14];
  float* out = (float*)d_out;

  float* ws = (float*)d_ws;
  float* pre_f = ws;                               // [T][512]
  float* pre_b = pre_f + (size_t)T_LEN * G4;       // [T][512]
  float* hcat  = pre_b + (size_t)T_LEN * G4;       // [T][256]
  float* feats32 = hcat + (size_t)T_LEN * 2 * HH;  // [T][32]
  unsigned char* bptr = (unsigned char*)(feats32 + (size_t)T_LEN * 32);
  unsigned char* maps = bptr + (size_t)T_LEN * KT;
  int* btags = (int*)(maps + 256 * KT);
  int* misc  = btags + 256;
  int* flags = misc + 8;                           // [0]=lstm done, [1]=vit done
  float* sink = (float*)(flags + 8);
  float* fvstore = pre_f;                          // [T][64], pre dead after k_lstm

  hipMemsetAsync(flags, 0, 8 * sizeof(int), stream);
  k_pre<<<512, 512, 0, stream>>>(sentence, embed, Wih_f, bih_f, bhh_f,
                                 Wih_b, bih_b, bhh_b, pre_f, pre_b);
  k_lstm<<<256, 512, 0, stream>>>(Whh_f, Whh_b, h0, c0, pre_f, pre_b, hcat,
                                  flags + 0, sink);
  k_feats<<<256, 256, 0, stream>>>(hcat, Wout, bout, feats32);
  k_vit_fwd<<<256, 64, 0, stream>>>(feats32, trans, fvstore, out, misc,
                                    flags + 1, sink);
  k_bptr<<<256, 256, 0, stream>>>(fvstore, trans, bptr);
  k_compose<<<256, 64, 0, stream>>>(bptr, maps);
  k_backscan<<<1, 64, 0, stream>>>(maps, misc, btags);
  k_backeval<<<256, 64, 0, stream>>>(bptr, btags, out);
}